// Round 1
// 441.239 us; speedup vs baseline: 1.0621x; 1.0621x over previous
//
#include <hip/hip_runtime.h>

// ---------------------------------------------------------------------------
// HyperMoMixLinear on MI355X.
//  K1 compress (+fused Wconv1):  c = silu(x@Wc+bc); convert W1b(+b1b) -> Wt
//  K2 hyper:     H = silu(c@[W1a|W2a|Wm1]+b), biasout = c@Wb+bb   (N=3328)
//  K3 prep:      coeffs=softmax(mixh@Wm2+bm2), ratio=c@Wr+br, G=coeff*h
//  K4 biggemm:   M1 = G1@Wt  [512,1056]@[1056,32768], both bf16 unit layout
//  K6 monarch1 (+fused Wconv2):  x1o = einsum(x, M1) -> XT; convert W2b -> Wt
//  K5 biggemm:   M2 = G2@Wt   (reuses M buffer)
//  K7 monarch2:  out = einsum(XT, M2)*ratio + biasout
//
// R5 change: W fp32->bf16 conversion hoisted OUT of biggemm into a one-shot
// transposing pass (unit layout: 16B unit = 8 consecutive k of one column;
// bias rows folded in as k-octet 128, zeros 129..131). The pass is fused into
// the under-occupied k1 (32 blocks) and monarch1 (512 blocks) launches so its
// BW cost hides on otherwise-idle CUs. biggemm is rebuilt as the proven m97
// structure: global_load_lds staging of BOTH operands (no VGPR round trip,
// no per-kt cvt), single-buffered 32KB LDS, 2 barriers/kt, 128x128 tile,
// XCD-swizzled grid (4 m-blocks sharing a W panel land on one XCD's L2).
// Workspace high-water: ~112 MB (Wt 69.2 MB reused for W1b then W2b).
// ---------------------------------------------------------------------------

typedef __bf16 bf16x8 __attribute__((ext_vector_type(8)));
typedef __bf16 bf16x2 __attribute__((ext_vector_type(2)));
typedef float  fx4    __attribute__((ext_vector_type(4)));

#define NN 32768

__device__ __forceinline__ unsigned short f2bf(float f) {
  union { __bf16 b; unsigned short u; } c; c.b = (__bf16)f; return c.u;
}
__device__ __forceinline__ unsigned pk2(float lo, float hi) {
  bf16x2 v; v[0] = (__bf16)lo; v[1] = (__bf16)hi;
  union { bf16x2 v; unsigned u; } c; c.v = v; return c.u;
}
__device__ __forceinline__ float b2f(unsigned short s) {
  union { unsigned u; float f; } v; v.u = ((unsigned)s) << 16; return v.f;
}
__device__ __forceinline__ void up8(uint4 h, float* f) {
  f[0] = b2f((unsigned short)(h.x & 0xFFFF)); f[1] = b2f((unsigned short)(h.x >> 16));
  f[2] = b2f((unsigned short)(h.y & 0xFFFF)); f[3] = b2f((unsigned short)(h.y >> 16));
  f[4] = b2f((unsigned short)(h.z & 0xFFFF)); f[5] = b2f((unsigned short)(h.z >> 16));
  f[6] = b2f((unsigned short)(h.w & 0xFFFF)); f[7] = b2f((unsigned short)(h.w >> 16));
}
__device__ __forceinline__ uint4 scale8(uint4 h, float cv) {
  uint4 u;
  u.x = pk2(b2f((unsigned short)(h.x & 0xFFFF)) * cv, b2f((unsigned short)(h.x >> 16)) * cv);
  u.y = pk2(b2f((unsigned short)(h.y & 0xFFFF)) * cv, b2f((unsigned short)(h.y >> 16)) * cv);
  u.z = pk2(b2f((unsigned short)(h.z & 0xFFFF)) * cv, b2f((unsigned short)(h.z >> 16)) * cv);
  u.w = pk2(b2f((unsigned short)(h.w & 0xFFFF)) * cv, b2f((unsigned short)(h.w >> 16)) * cv);
  return u;
}
__device__ __forceinline__ float silu_f(float x) { return x / (1.f + __expf(-x)); }

__device__ __forceinline__ void gl2lds16(const void* g, void* l) {
  __builtin_amdgcn_global_load_lds(
      (const __attribute__((address_space(1))) unsigned int*)g,
      (__attribute__((address_space(3))) unsigned int*)l, 16, 0, 0);
}

#define MFMA(a, b, c) __builtin_amdgcn_mfma_f32_16x16x32_bf16((a), (b), (c), 0, 0, 0)

// ---------------------------------------------------------------------------
// W conversion body: fp32 W [1024, 32768] (+ bias rows bvec [4, 32768])
//   -> Wt unit layout: Wt[ur * NN + n] = uint4 of 8 bf16 {k=ur*8..ur*8+7, col n}
// ur 0..127 from W; ur 128 = bvec rows 0..3 (+ zeros); ur 129..131 = zeros.
// cb = conversion block index, 0..4223  (132 unit-rows x 32 column chunks).
// Reads fully coalesced (1 KiB/wave/instr); one-shot, BW-bound.
// ---------------------------------------------------------------------------
__device__ __forceinline__ void wconv_body(int cb, const float* __restrict__ W,
                                           const float* __restrict__ bvec,
                                           uint4* __restrict__ Wt) {
  const int ur = cb >> 5;                              // 0..131
  const int n0 = (cb & 31) * 1024 + threadIdx.x * 4;   // column (unit) index
  fx4 r[8];
  if (ur < 128) {
#pragma unroll
    for (int kk = 0; kk < 8; ++kk)
      r[kk] = *(const fx4*)(W + (size_t)(ur * 8 + kk) * NN + n0);
  } else {
#pragma unroll
    for (int kk = 0; kk < 8; ++kk) r[kk] = 0;
    if (ur == 128) {
#pragma unroll
      for (int kk = 0; kk < 4; ++kk)
        r[kk] = *(const fx4*)(bvec + (size_t)kk * NN + n0);
    }
  }
#pragma unroll
  for (int j = 0; j < 4; ++j) {
    uint4 u;
    u.x = pk2(r[0][j], r[1][j]); u.y = pk2(r[2][j], r[3][j]);
    u.z = pk2(r[4][j], r[5][j]); u.w = pk2(r[6][j], r[7][j]);
    Wt[(size_t)ur * NN + n0 + j] = u;
  }
}

// ---------------------------------------------------------------------------
// K1: c = silu(x @ Wc + bc).  M=512,K=1024,N=256.  BM=BN=64, BK=64, pipelined.
// Fused: blocks >= 32 convert W1b -> Wt (chip otherwise idle during k1).
// ---------------------------------------------------------------------------
__global__ __launch_bounds__(256) void k1_compress(
    const float* __restrict__ x, const float* __restrict__ Wc,
    const float* __restrict__ bc, uint4* __restrict__ c_u4,
    const float* __restrict__ W1b, const float* __restrict__ b1b,
    uint4* __restrict__ Wt) {
  const int b = blockIdx.x;
  if (b >= 32) { wconv_body(b - 32, W1b, b1b, Wt); return; }
  const int tid = threadIdx.x;
  const int m0 = (b & 7) * 64, n0 = (b >> 3) * 64;
  __shared__ uint4 As[8 * 64];
  __shared__ uint4 Bs[8 * 65];
  const bf16x8* Af = reinterpret_cast<const bf16x8*>(As);
  const bf16x8* Bf = reinterpret_cast<const bf16x8*>(Bs);
  uint2* Bs2 = reinterpret_cast<uint2*>(Bs);
  const int lane = tid & 63, w = tid >> 6;
  const int q = lane >> 4, rr = lane & 15;
  const int wm = (w >> 1) * 32, wn = (w & 1) * 32;
  const int arun = tid & 7, amb = tid >> 3;      // A staging ownership
  const int kgrp = tid & 15, colg = tid >> 4;    // B staging ownership
  fx4 a00 = 0, a01 = 0, a10 = 0, a11 = 0;
  fx4 areg[4], breg[4];

  // prefetch kt=0
#pragma unroll
  for (int s = 0; s < 2; ++s) {
    const float* src = x + (size_t)(m0 + amb + 32 * s) * 1024 + arun * 8;
    areg[2 * s] = *(const fx4*)src;
    areg[2 * s + 1] = *(const fx4*)(src + 4);
  }
#pragma unroll
  for (int kk = 0; kk < 4; ++kk)
    breg[kk] = *(const fx4*)(Wc + (size_t)(kgrp * 4 + kk) * 256 + n0 + colg * 4);

  for (int kt = 0; kt < 16; ++kt) {
    __syncthreads();
#pragma unroll
    for (int s = 0; s < 2; ++s) {
      uint4 u;
      u.x = pk2(areg[2 * s][0], areg[2 * s][1]);
      u.y = pk2(areg[2 * s][2], areg[2 * s][3]);
      u.z = pk2(areg[2 * s + 1][0], areg[2 * s + 1][1]);
      u.w = pk2(areg[2 * s + 1][2], areg[2 * s + 1][3]);
      As[arun * 64 + amb + 32 * s] = u;
    }
#pragma unroll
    for (int j = 0; j < 4; ++j) {
      uint2 u;
      u.x = pk2(breg[0][j], breg[1][j]);
      u.y = pk2(breg[2][j], breg[3][j]);
      Bs2[(((kgrp >> 1) * 65 + colg * 4 + j) << 1) + (kgrp & 1)] = u;
    }
    __syncthreads();
    if (kt < 15) {
      const int k0 = (kt + 1) * 64;
#pragma unroll
      for (int s = 0; s < 2; ++s) {
        const float* src = x + (size_t)(m0 + amb + 32 * s) * 1024 + k0 + arun * 8;
        areg[2 * s] = *(const fx4*)src;
        areg[2 * s + 1] = *(const fx4*)(src + 4);
      }
#pragma unroll
      for (int kk = 0; kk < 4; ++kk)
        breg[kk] = *(const fx4*)(Wc + (size_t)(k0 + kgrp * 4 + kk) * 256 + n0 + colg * 4);
    }
#pragma unroll
    for (int ks = 0; ks < 2; ++ks) {
      const int roA = (ks * 4 + q) * 64, roB = (ks * 4 + q) * 65;
      bf16x8 fa0 = Af[roA + wm + rr];
      bf16x8 fa1 = Af[roA + wm + 16 + rr];
      bf16x8 fb0 = Bf[roB + wn + rr];
      bf16x8 fb1 = Bf[roB + wn + 16 + rr];
      a00 = MFMA(fa0, fb0, a00); a01 = MFMA(fa0, fb1, a01);
      a10 = MFMA(fa1, fb0, a10); a11 = MFMA(fa1, fb1, a11);
    }
  }
  __syncthreads();
  {  // tail: A const-one channel, B row = bc
    const int r4 = tid >> 6, m = tid & 63;
    uint4 u; u.x = (r4 == 0) ? 0x3F80u : 0u; u.y = 0; u.z = 0; u.w = 0;
    As[r4 * 64 + m] = u;
    uint4 ub; ub.x = (r4 == 0) ? (unsigned)f2bf(bc[n0 + m]) : 0u;
    ub.y = 0; ub.z = 0; ub.w = 0;
    Bs[r4 * 65 + m] = ub;
  }
  __syncthreads();
  {
    bf16x8 fa0 = Af[q * 64 + wm + rr];
    bf16x8 fa1 = Af[q * 64 + wm + 16 + rr];
    bf16x8 fb0 = Bf[q * 65 + wn + rr];
    bf16x8 fb1 = Bf[q * 65 + wn + 16 + rr];
    a00 = MFMA(fa0, fb0, a00); a01 = MFMA(fa0, fb1, a01);
    a10 = MFMA(fa1, fb0, a10); a11 = MFMA(fa1, fb1, a11);
  }
  unsigned short* c16 = (unsigned short*)c_u4;
#pragma unroll
  for (int fi = 0; fi < 2; ++fi) {
#pragma unroll
    for (int fj = 0; fj < 2; ++fj) {
      fx4 v = (fi == 0) ? (fj == 0 ? a00 : a01) : (fj == 0 ? a10 : a11);
      const int cc = n0 + wn + fj * 16 + rr;
#pragma unroll
      for (int reg = 0; reg < 4; ++reg) {
        const int t = m0 + wm + fi * 16 + q * 4 + reg;
        c16[((size_t)(cc >> 3) * 512 + t) * 8 + (cc & 7)] = f2bf(silu_f(v[reg]));
      }
    }
  }
  if ((b >> 3) == 0) {  // const-one run 32 + zero runs 33..35
    const int r4 = tid >> 6, m = tid & 63;
    uint4 u; u.x = (r4 == 0) ? 0x3F80u : 0u; u.y = 0; u.z = 0; u.w = 0;
    c_u4[(size_t)(32 + r4) * 512 + m0 + m] = u;
  }
}

// ---------------------------------------------------------------------------
// K2: H = silu(c@{W1a,W2a,Wm1}+bias) -> unit layout, biasout = c@Wb+bb.
// M=512, K=256(+tail), N=3328. BM=BN=64, pipelined (A dbuf gl2lds, B regs).
// ---------------------------------------------------------------------------
__global__ __launch_bounds__(256) void k2_hyper(
    const uint4* __restrict__ c_u4,
    const float* __restrict__ W1a, const float* __restrict__ b1a,
    const float* __restrict__ W2a, const float* __restrict__ b2a,
    const float* __restrict__ Wm1, const float* __restrict__ bm1,
    const float* __restrict__ Wb, const float* __restrict__ bb,
    unsigned short* __restrict__ H, float* __restrict__ biasout) {
  const int tid = threadIdx.x;
  const int m0 = blockIdx.x * 64, n0 = blockIdx.y * 64;
  __shared__ uint4 As[2][8 * 64];
  __shared__ uint4 Bs[8 * 65];
  const bf16x8* Bf = reinterpret_cast<const bf16x8*>(Bs);
  uint2* Bs2 = reinterpret_cast<uint2*>(Bs);
  const int lane = tid & 63, w = tid >> 6;
  const int q = lane >> 4, rr = lane & 15;
  const int wm = (w >> 1) * 32, wn = (w & 1) * 32;
  const int kgrp = tid & 15, colg = tid >> 4;

  const float* bbase; const float* biasv; int bstride;
  if (n0 < 1024) {
    const int kx = n0 >> 8;
    bbase = W1a + (size_t)kx * 65536 + (n0 & 255); bstride = 256;
    biasv = b1a + kx * 256 + (n0 & 255);
  } else if (n0 < 2048) {
    const int mm = n0 - 1024; const int kx = mm >> 8;
    bbase = W2a + (size_t)kx * 65536 + (mm & 255); bstride = 256;
    biasv = b2a + kx * 256 + (mm & 255);
  } else if (n0 < 2304) {
    bbase = Wm1 + (n0 - 2048); bstride = 256; biasv = bm1 + (n0 - 2048);
  } else {
    bbase = Wb + (n0 - 2304); bstride = 1024; biasv = bb + (n0 - 2304);
  }

  fx4 a00 = 0, a01 = 0, a10 = 0, a11 = 0;
  fx4 breg[4];
#pragma unroll
  for (int kk = 0; kk < 4; ++kk)
    breg[kk] = *(const fx4*)(bbase + (size_t)(kgrp * 4 + kk) * bstride + colg * 4);
#pragma unroll
  for (int s = 0; s < 2; ++s) {
    const int run = w * 2 + s;
    gl2lds16(c_u4 + (size_t)run * 512 + m0 + lane, (void*)(&As[0][run * 64]));
  }
  int cur = 0;
  for (int kt = 0; kt < 4; ++kt) {
    __syncthreads();
#pragma unroll
    for (int j = 0; j < 4; ++j) {
      uint2 u;
      u.x = pk2(breg[0][j], breg[1][j]);
      u.y = pk2(breg[2][j], breg[3][j]);
      Bs2[(((kgrp >> 1) * 65 + colg * 4 + j) << 1) + (kgrp & 1)] = u;
    }
    __syncthreads();
    if (kt < 3) {
#pragma unroll
      for (int s = 0; s < 2; ++s) {
        const int run = w * 2 + s;
        gl2lds16(c_u4 + (size_t)((kt + 1) * 8 + run) * 512 + m0 + lane,
                 (void*)(&As[cur ^ 1][run * 64]));
      }
#pragma unroll
      for (int kk = 0; kk < 4; ++kk)
        breg[kk] = *(const fx4*)(bbase + (size_t)((kt + 1) * 64 + kgrp * 4 + kk) * bstride + colg * 4);
    }
    const bf16x8* Af = reinterpret_cast<const bf16x8*>(As[cur]);
#pragma unroll
    for (int ks = 0; ks < 2; ++ks) {
      const int roA = (ks * 4 + q) * 64, roB = (ks * 4 + q) * 65;
      bf16x8 fa0 = Af[roA + wm + rr];
      bf16x8 fa1 = Af[roA + wm + 16 + rr];
      bf16x8 fb0 = Bf[roB + wn + rr];
      bf16x8 fb1 = Bf[roB + wn + 16 + rr];
      a00 = MFMA(fa0, fb0, a00); a01 = MFMA(fa0, fb1, a01);
      a10 = MFMA(fa1, fb0, a10); a11 = MFMA(fa1, fb1, a11);
    }
    cur ^= 1;
  }
  __syncthreads();
  {  // tail (cur==0)
    gl2lds16(c_u4 + (size_t)(32 + w) * 512 + m0 + lane, (void*)(&As[0][w * 64]));
    const int r4 = tid >> 6, col = tid & 63;
    uint4 ub; ub.x = (r4 == 0) ? (unsigned)f2bf(biasv[col]) : 0u;
    ub.y = 0; ub.z = 0; ub.w = 0;
    Bs[r4 * 65 + col] = ub;
  }
  __syncthreads();
  {
    const bf16x8* Af = reinterpret_cast<const bf16x8*>(As[0]);
    bf16x8 fa0 = Af[q * 64 + wm + rr];
    bf16x8 fa1 = Af[q * 64 + wm + 16 + rr];
    bf16x8 fb0 = Bf[q * 65 + wn + rr];
    bf16x8 fb1 = Bf[q * 65 + wn + 16 + rr];
    a00 = MFMA(fa0, fb0, a00); a01 = MFMA(fa0, fb1, a01);
    a10 = MFMA(fa1, fb0, a10); a11 = MFMA(fa1, fb1, a11);
  }
#pragma unroll
  for (int fi = 0; fi < 2; ++fi) {
#pragma unroll
    for (int fj = 0; fj < 2; ++fj) {
      fx4 v = (fi == 0) ? (fj == 0 ? a00 : a01) : (fj == 0 ? a10 : a11);
      const int cc = n0 + wn + fj * 16 + rr;
#pragma unroll
      for (int reg = 0; reg < 4; ++reg) {
        const int t = m0 + wm + fi * 16 + q * 4 + reg;
        if (n0 < 2304)
          H[(((size_t)(cc >> 3) * 512 + t) << 3) + (cc & 7)] = f2bf(silu_f(v[reg]));
        else
          biasout[(size_t)t * 1024 + (cc - 2304)] = v[reg];
      }
    }
  }
}

// ---------------------------------------------------------------------------
// K3: coeffs = softmax(mixh@Wm2+bm2); ratio = c@Wr+br; G = coeff*h (+tails).
// ---------------------------------------------------------------------------
__global__ __launch_bounds__(256) void k3_prep(
    const uint4* __restrict__ Hu, const uint4* __restrict__ c_u4,
    const float* __restrict__ Wm2, const float* __restrict__ bm2,
    const float* __restrict__ Wr, const float* __restrict__ br,
    uint4* __restrict__ G1u, uint4* __restrict__ G2u, float* __restrict__ ratio) {
  const int tid = threadIdx.x;
  const int tg = blockIdx.x & 7, dgrp = blockIdx.x >> 3;
  const int t0 = tg * 64;
  __shared__ float sWm2[1024];
  __shared__ float sWr[256];
  __shared__ float part[64][4][4];
  __shared__ float rp[64][4];
  __shared__ float cf[64][4];
  ((fx4*)sWm2)[tid] = ((const fx4*)Wm2)[tid];
  if (tid < 64) ((fx4*)sWr)[tid] = ((const fx4*)Wr)[tid];
  __syncthreads();
  const int tl = tid >> 2, kx = tid & 3;
  {
    float pe0 = 0, pe1 = 0, pe2 = 0, pe3 = 0, pr = 0;
#pragma unroll
    for (int i = 0; i < 8; ++i) {
      uint4 h  = Hu[(size_t)(256 + kx * 8 + i) * 512 + t0 + tl];
      uint4 cu = c_u4[(size_t)(kx * 8 + i) * 512 + t0 + tl];
      float hf[8], cv[8];
      up8(h, hf); up8(cu, cv);
#pragma unroll
      for (int j = 0; j < 8; ++j) {
        const int ch = kx * 64 + i * 8 + j;
        pe0 += hf[j] * sWm2[ch * 4 + 0];
        pe1 += hf[j] * sWm2[ch * 4 + 1];
        pe2 += hf[j] * sWm2[ch * 4 + 2];
        pe3 += hf[j] * sWm2[ch * 4 + 3];
        pr  += cv[j] * sWr[ch];
      }
    }
    part[tl][kx][0] = pe0; part[tl][kx][1] = pe1;
    part[tl][kx][2] = pe2; part[tl][kx][3] = pe3;
    rp[tl][kx] = pr;
  }
  __syncthreads();
  if (tid < 64) {
    float l[4];
#pragma unroll
    for (int e = 0; e < 4; ++e)
      l[e] = part[tid][0][e] + part[tid][1][e] + part[tid][2][e] + part[tid][3][e] + bm2[e];
    float m = fmaxf(fmaxf(l[0], l[1]), fmaxf(l[2], l[3]));
    float e0 = __expf(l[0] - m), e1 = __expf(l[1] - m);
    float e2 = __expf(l[2] - m), e3 = __expf(l[3] - m);
    float den = e0 + e1 + e2 + e3;
    cf[tid][0] = e0 / den; cf[tid][1] = e1 / den;
    cf[tid][2] = e2 / den; cf[tid][3] = e3 / den;
    if (dgrp == 0)
      ratio[t0 + tid] = rp[tid][0] + rp[tid][1] + rp[tid][2] + rp[tid][3] + br[0];
  }
  __syncthreads();
  const int tl2 = tid & 63, sub = tid >> 6;
#pragma unroll
  for (int i = 0; i < 4; ++i) {
    const int dg = dgrp * 16 + sub * 4 + i;
    const float cv = cf[tl2][dg >> 5];
    uint4 h1 = Hu[(size_t)dg * 512 + t0 + tl2];
    G1u[(size_t)dg * 512 + t0 + tl2] = scale8(h1, cv);
    uint4 h2 = Hu[(size_t)(128 + dg) * 512 + t0 + tl2];
    G2u[(size_t)dg * 512 + t0 + tl2] = scale8(h2, cv);
  }
  if (dgrp == 0) {
    if (tid < 64) {  // coeff run 128
      uint4 u;
      u.x = pk2(cf[tid][0], cf[tid][1]);
      u.y = pk2(cf[tid][2], cf[tid][3]);
      u.z = 0; u.w = 0;
      G1u[(size_t)128 * 512 + t0 + tid] = u;
      G2u[(size_t)128 * 512 + t0 + tid] = u;
    } else {  // zero runs 129..131
      const int idx = tid - 64;
      uint4 z; z.x = 0; z.y = 0; z.z = 0; z.w = 0;
      G1u[(size_t)(129 + (idx >> 6)) * 512 + t0 + (idx & 63)] = z;
      G2u[(size_t)(129 + (idx >> 6)) * 512 + t0 + (idx & 63)] = z;
    }
  }
}

// ---------------------------------------------------------------------------
// K4/K5: M = G @ Wt, both operands bf16 unit layout. M=512,K=1056,N=32768.
// BM=BN=128, BK=64, 256 threads, m97-proven structure: global_load_lds stages
// both tiles into single-buffered LDS (32 KB), 2 barriers per K-step,
// 32 MFMA/kt/wave. Coeff-mixed bias handled by k-octets 128..131 (in Wt/G).
// M stored permuted: [t][i*1024 + g*32 + o]  (cc = g*1024+i*32+o).
// ---------------------------------------------------------------------------
__global__ __launch_bounds__(256) void k_biggemm(
    const uint4* __restrict__ Gu, const uint4* __restrict__ Wt,
    unsigned short* __restrict__ Mout) {
  const int tid = threadIdx.x;
  const int p = blockIdx.x;
  const int xcd = p & 7, slot = p >> 3;
  const int m0 = (slot & 3) * 128;
  const int n0 = ((slot >> 2) * 8 + xcd) * 128;
  __shared__ uint4 As[8 * 128];
  __shared__ uint4 Bs[8 * 128];
  const bf16x8* Af = reinterpret_cast<const bf16x8*>(As);
  const bf16x8* Bf = reinterpret_cast<const bf16x8*>(Bs);
  const int lane = tid & 63, w = tid >> 6;
  const int q = lane >> 4, rr = lane & 15;
  const int wm = (w >> 1) * 64, wn = (w & 1) * 64;

  fx4 acc[4][4];
#pragma unroll
  for (int i = 0; i < 4; ++i)
#pragma unroll
    for (int j = 0; j < 4; ++j) acc[i][j] = 0;

  for (int kt = 0; kt < 16; ++kt) {
    __syncthreads();  // previous compute's LDS reads done
#pragma unroll
    for (int s = 0; s < 4; ++s) {
      const int idx = w * 4 + s;           // 0..15
      const int run = idx >> 1, hf = (idx & 1) * 64;
      gl2lds16(Gu + (size_t)(kt * 8 + run) * 512 + m0 + hf + lane,
               (void*)(&As[run * 128 + hf]));
      gl2lds16(Wt + (size_t)(kt * 8 + run) * NN + n0 + hf + lane,
               (void*)(&Bs[run * 128 + hf]));
    }
    __syncthreads();  // staging drained (compiler emits vmcnt(0) before barrier)
#pragma unroll
    for (int ks = 0; ks < 2; ++ks) {
      const int ro = (ks * 4 + q) * 128;
      bf16x8 a[4], b[4];
#pragma unroll
      for (int f = 0; f < 4; ++f) {
        a[f] = Af[ro + wm + f * 16 + rr];
        b[f] = Bf[ro + wn + f * 16 + rr];
      }
#pragma unroll
      for (int fi = 0; fi < 4; ++fi)
#pragma unroll
        for (int fj = 0; fj < 4; ++fj) acc[fi][fj] = MFMA(a[fi], b[fj], acc[fi][fj]);
    }
  }
  // tail half K-step: k-octets 128..131 (coeffs x bias rows + zeros)
  __syncthreads();
#pragma unroll
  for (int s = 0; s < 2; ++s) {
    const int idx = w * 2 + s;             // 0..7
    const int run = idx >> 1, hf = (idx & 1) * 64;
    gl2lds16(Gu + (size_t)(128 + run) * 512 + m0 + hf + lane,
             (void*)(&As[run * 128 + hf]));
    gl2lds16(Wt + (size_t)(128 + run) * NN + n0 + hf + lane,
             (void*)(&Bs[run * 128 + hf]));
  }
  __syncthreads();
  {
    const int ro = q * 128;
    bf16x8 a[4], b[4];
#pragma unroll
    for (int f = 0; f < 4; ++f) {
      a[f] = Af[ro + wm + f * 16 + rr];
      b[f] = Bf[ro + wn + f * 16 + rr];
    }
#pragma unroll
    for (int fi = 0; fi < 4; ++fi)
#pragma unroll
      for (int fj = 0; fj < 4; ++fj) acc[fi][fj] = MFMA(a[fi], b[fj], acc[fi][fj]);
  }
  // epilogue: permuted bf16 store  cc=(g,i,o) -> pc = i*1024 + g*32 + o
#pragma unroll
  for (int fi = 0; fi < 4; ++fi) {
    const int tb = m0 + wm + fi * 16 + q * 4;
#pragma unroll
    for (int fj = 0; fj < 4; ++fj) {
      const fx4 v = acc[fi][fj];
      const int cc = n0 + wn + fj * 16 + rr;
      const int pc = ((cc >> 5) & 31) * 1024 + (cc >> 10) * 32 + (cc & 31);
#pragma unroll
      for (int reg = 0; reg < 4; ++reg)
        Mout[(size_t)(tb + reg) * NN + pc] = f2bf(v[reg]);
    }
  }
}

// ---------------------------------------------------------------------------
// K6: x1o[g][o] = sum_i x[g*32+i] * M1p[t, i*1024+g*32+o]; XT[t][o*32+g].
// 1 token/block, i-split 2-way + LDS reduce; 512 blocks.
// Fused: blocks >= 512 convert W2b -> Wt (ready for K5; Wt reuse is safe
// because K4 completed before this launch).
// ---------------------------------------------------------------------------
__global__ __launch_bounds__(256) void k_monarch1(
    const float* __restrict__ x, const unsigned short* __restrict__ M1p,
    float* __restrict__ XT,
    const float* __restrict__ W2b, const float* __restrict__ b2b,
    uint4* __restrict__ Wt) {
  const int b = blockIdx.x;
  if (b >= 512) { wconv_body(b - 512, W2b, b2b, Wt); return; }
  const int tt = b, tid = threadIdx.x;
  const int h = tid >> 7, t2 = tid & 127;
  __shared__ float xs[1024];
  __shared__ float xo[2][1024];
  *(float4*)&xs[tid * 4] = *(const float4*)&x[(size_t)tt * 1024 + tid * 4];
  __syncthreads();
  const int g = t2 >> 2, ob = (t2 & 3) * 8;
  const unsigned short* mrow =
      M1p + (size_t)tt * NN + (size_t)h * 16 * 1024 + g * 32 + ob;
  float acc[8] = {0, 0, 0, 0, 0, 0, 0, 0};
#pragma unroll
  for (int i = 0; i < 16; ++i) {
    uint4 mv = *(const uint4*)&mrow[(size_t)i * 1024];
    float mf[8]; up8(mv, mf);
    const float xv = xs[g * 32 + h * 16 + i];
#pragma unroll
    for (int j = 0; j < 8; ++j) acc[j] += xv * mf[j];
  }
  // transposed store builds XT[o*32+g]
#pragma unroll
  for (int j = 0; j < 8; ++j) xo[h][(ob + j) * 32 + g] = acc[j];
  __syncthreads();
  {
    const int base = tid * 4;
    float4 v0 = *(const float4*)&xo[0][base];
    float4 v1 = *(const float4*)&xo[1][base];
    float4 o; o.x = v0.x + v1.x; o.y = v0.y + v1.y;
    o.z = v0.z + v1.z; o.w = v0.w + v1.w;
    *(float4*)&XT[(size_t)tt * 1024 + base] = o;
  }
}

// ---------------------------------------------------------------------------
// K7: out[t, g*32+o] = (sum_i XT[t][g*32+i]*M2p[t, i*1024+g*32+o])*ratio + biasout
// 1 token/block, i-split 2-way + LDS reduce; 512 blocks. NATURAL output order.
// ---------------------------------------------------------------------------
__global__ __launch_bounds__(256) void k_monarch2(
    const unsigned short* __restrict__ M2p, const float* __restrict__ XT,
    const float* __restrict__ biasout, const float* __restrict__ ratio,
    float* __restrict__ out) {
  const int tt = blockIdx.x, tid = threadIdx.x;
  const int h = tid >> 7, t2 = tid & 127;
  __shared__ float xs[1024];
  __shared__ float xo[2][1024];
  *(float4*)&xs[tid * 4] = *(const float4*)&XT[(size_t)tt * 1024 + tid * 4];
  __syncthreads();
  const int g = t2 >> 2, ob = (t2 & 3) * 8;
  const unsigned short* mrow =
      M2p + (size_t)tt * NN + (size_t)h * 16 * 1024 + g * 32 + ob;
  float acc[8] = {0, 0, 0, 0, 0, 0, 0, 0};
#pragma unroll
  for (int i = 0; i < 16; ++i) {
    uint4 mv = *(const uint4*)&mrow[(size_t)i * 1024];
    float mf[8]; up8(mv, mf);
    const float xv = xs[g * 32 + h * 16 + i];
#pragma unroll
    for (int j = 0; j < 8; ++j) acc[j] += xv * mf[j];
  }
#pragma unroll
  for (int j = 0; j < 8; ++j) xo[h][g * 32 + ob + j] = acc[j];
  __syncthreads();
  {
    const float r = ratio[tt];
    const int base = tid * 4;
    float4 v0 = *(const float4*)&xo[0][base];
    float4 v1 = *(const float4*)&xo[1][base];
    float4 bo = *(const float4*)&biasout[(size_t)tt * 1024 + base];
    float4 o;
    o.x = (v0.x + v1.x) * r + bo.x; o.y = (v0.y + v1.y) * r + bo.y;
    o.z = (v0.z + v1.z) * r + bo.z; o.w = (v0.w + v1.w) * r + bo.w;
    *(float4*)&out[(size_t)tt * 1024 + base] = o;
  }
}

// ---------------------------------------------------------------------------
extern "C" void kernel_launch(void* const* d_in, const int* in_sizes, int n_in,
                              void* d_out, int out_size, void* d_ws, size_t ws_size,
                              hipStream_t stream) {
  (void)in_sizes; (void)n_in; (void)out_size; (void)ws_size;
  const float* x   = (const float*)d_in[0];
  const float* Wc  = (const float*)d_in[1];
  const float* bc  = (const float*)d_in[2];
  const float* W1a = (const float*)d_in[3];
  const float* b1a = (const float*)d_in[4];
  const float* W1b = (const float*)d_in[5];
  const float* b1b = (const float*)d_in[6];
  const float* W2a = (const float*)d_in[7];
  const float* b2a = (const float*)d_in[8];
  const float* W2b = (const float*)d_in[9];
  const float* b2b = (const float*)d_in[10];
  const float* Wm1 = (const float*)d_in[11];
  const float* bm1 = (const float*)d_in[12];
  const float* Wm2 = (const float*)d_in[13];
  const float* bm2 = (const float*)d_in[14];
  const float* Wb  = (const float*)d_in[15];
  const float* bb  = (const float*)d_in[16];
  const float* Wr  = (const float*)d_in[17];
  const float* br  = (const float*)d_in[18];
  float* out = (float*)d_out;

  char* ws = (char*)d_ws;
  uint4* c_u4            = (uint4*)(ws + 0);                 // 36*512*16  = 294912
  unsigned short* H      = (unsigned short*)(ws + 294912);   // 288*512*16 = 2359296
  float* biasout         = (float*)(ws + 2654208);           // 512*1024*4 = 2097152
  uint4* G1u             = (uint4*)(ws + 4751360);           // 132*512*16 = 1081344
  uint4* G2u             = (uint4*)(ws + 5832704);           // 132*512*16 = 1081344
  float* ratio           = (float*)(ws + 6914048);           // 512*4 (+pad)
  float* XT              = (float*)(ws + 6918144);           // 512*1024*4 = 2097152
  unsigned short* M      = (unsigned short*)(ws + 9015296);  // 512*32768*2 = 33554432
  uint4* Wt              = (uint4*)(ws + 42569728);          // 132*32768*16 = 69206016
                                                             // high-water ~111.8 MB

  // k1 (32 blocks) + W1b conversion (4224 blocks) share one launch
  k1_compress<<<4256, 256, 0, stream>>>(x, Wc, bc, c_u4, W1b, b1b, Wt);
  k2_hyper<<<dim3(8, 52), 256, 0, stream>>>(c_u4, W1a, b1a, W2a, b2a, Wm1, bm1,
                                            Wb, bb, H, biasout);
  k3_prep<<<64, 256, 0, stream>>>((const uint4*)H, c_u4, Wm2, bm2, Wr, br,
                                  G1u, G2u, ratio);
  k_biggemm<<<1024, 256, 0, stream>>>(G1u, Wt, M);
  // monarch1 (512 blocks) + W2b conversion (4224 blocks) share one launch
  k_monarch1<<<4736, 256, 0, stream>>>(x, M, XT, W2b, b2b, Wt);
  k_biggemm<<<1024, 256, 0, stream>>>(G2u, Wt, M);
  k_monarch2<<<512, 256, 0, stream>>>(M, XT, biasout, ratio, out);
}